// Round 1
// baseline (1118.219 us; speedup 1.0000x reference)
//
#include <hip/hip_runtime.h>
#include <cstdint>
#include <cstddef>

#define DIN 128   // feature width of all layer inputs (and Q/K/V width = H*DH)
#define QKVS_STRIDE 512

// ---------------- CSR build ----------------
__global__ void k_zero(int* __restrict__ a, int n){
  int i = blockIdx.x*blockDim.x + threadIdx.x;
  if(i<n) a[i]=0;
}

__global__ void k_count(const int* __restrict__ dst, int* __restrict__ deg, int E){
  int i = blockIdx.x*blockDim.x + threadIdx.x;
  if(i<E) atomicAdd(&deg[dst[i]], 1);
}

__global__ void k_scan1(const int* __restrict__ deg, int* __restrict__ offs,
                        int* __restrict__ part, int n){
  __shared__ int sm[256];
  int t = threadIdx.x; int g = blockIdx.x*256 + t;
  int v = (g<n)? deg[g] : 0;
  sm[t] = v;
  for(int o=1;o<256;o<<=1){
    __syncthreads();
    int x = (t>=o)? sm[t-o] : 0;
    __syncthreads();
    sm[t] += x;
  }
  __syncthreads();
  if(g<n) offs[g+1] = sm[t];
  if(t==255) part[blockIdx.x] = sm[255];
}

__global__ void k_scan2(int* __restrict__ part, int nb){
  __shared__ int sm[256];
  int t=threadIdx.x;
  int v = (t<nb)? part[t] : 0;
  sm[t]=v;
  for(int o=1;o<256;o<<=1){ __syncthreads(); int x=(t>=o)?sm[t-o]:0; __syncthreads(); sm[t]+=x; }
  __syncthreads();
  if(t<nb) part[t] = sm[t]-v;  // exclusive prefix of block totals
}

__global__ void k_scan3(int* __restrict__ offs, const int* __restrict__ part, int n){
  int t=threadIdx.x; int g=blockIdx.x*256+t;
  if(g<n) offs[g+1] += part[blockIdx.x];
  if(g==0) offs[0]=0;
}

__global__ void k_scatter(const int* __restrict__ src, const int* __restrict__ dst,
                          const int* __restrict__ offs, int* __restrict__ cur,
                          int* __restrict__ srcs, int E){
  int i=blockIdx.x*blockDim.x+threadIdx.x;
  if(i<E){
    int d = dst[i];
    int p = atomicAdd(&cur[d],1);
    srcs[offs[d]+p] = src[i];
  }
}

// ---------------- fused QKVS GEMM (fp32) ----------------
// out[N][512]: cols 0..127 = Q, 128..255 = K, 256..383 = V, 384.. = S (ws_cols wide)
// grid: (8, row_tiles): blockIdx.x -> mat = bx>>1 (0..3), col-tile = bx&1
__global__ __launch_bounds__(256,2) void k_gemm(
  const float* __restrict__ X, int nrows,
  const float* __restrict__ Wq, const float* __restrict__ bq,
  const float* __restrict__ Wk, const float* __restrict__ bk,
  const float* __restrict__ Wv, const float* __restrict__ bv,
  const float* __restrict__ Ws, const float* __restrict__ bs,
  int ws_cols, float* __restrict__ out)
{
  __shared__ float Xs[64][128];
  __shared__ float Wsh[128][64];
  int t = threadIdx.x;
  int mat = blockIdx.x >> 1, ct = blockIdx.x & 1;
  int wcols = (mat==3)? ws_cols : 128;
  int col0 = ct*64;
  if(col0 >= wcols) return;
  const float* W; const float* b;
  if(mat==0){W=Wq;b=bq;} else if(mat==1){W=Wk;b=bk;} else if(mat==2){W=Wv;b=bv;} else {W=Ws;b=bs;}
  int row0 = blockIdx.y*64;
  {
    int r = t>>5, c4 = (t&31)<<2;
    #pragma unroll
    for(int j=0;j<8;j++){
      int rr = r + (j<<3); int gr = row0+rr;
      float4 v = make_float4(0.f,0.f,0.f,0.f);
      if(gr < nrows) v = *(const float4*)(X + (size_t)gr*DIN + c4);
      *(float4*)&Xs[rr][c4] = v;
    }
    int k0 = t>>4, cc = (t&15)<<2;
    #pragma unroll
    for(int j=0;j<8;j++){
      int kk = k0 + (j<<4); int gc = col0 + cc;
      float4 v = make_float4(0.f,0.f,0.f,0.f);
      if(gc+3 < wcols) v = *(const float4*)(W + (size_t)kk*wcols + gc);
      *(float4*)&Wsh[kk][cc] = v;
    }
  }
  __syncthreads();
  int tr = t>>4, tc = t&15;
  int r0 = tr<<2, c0 = tc<<2;
  float acc[4][4];
  #pragma unroll
  for(int i=0;i<4;i++){ acc[i][0]=0.f; acc[i][1]=0.f; acc[i][2]=0.f; acc[i][3]=0.f; }
  #pragma unroll 8
  for(int k=0;k<128;k++){
    float4 w4 = *(const float4*)&Wsh[k][c0];
    #pragma unroll
    for(int i=0;i<4;i++){
      float x = Xs[r0+i][k];
      acc[i][0] += x*w4.x; acc[i][1] += x*w4.y; acc[i][2] += x*w4.z; acc[i][3] += x*w4.w;
    }
  }
  int cbase = col0 + c0;
  if(cbase+3 < wcols || wcols==128){
    float4 bb = *(const float4*)(b + cbase);
    #pragma unroll
    for(int i=0;i<4;i++){
      int gr = row0 + r0 + i;
      if(gr < nrows){
        float4 o = make_float4(acc[i][0]+bb.x, acc[i][1]+bb.y, acc[i][2]+bb.z, acc[i][3]+bb.w);
        *(float4*)(out + (size_t)gr*QKVS_STRIDE + mat*128 + cbase) = o;
      }
    }
  }
}

// ---------------- per-node attention (online softmax, CSR) ----------------
// one wave (64 lanes) per dst node; 4 waves / 256-thread block.
// logit phase: lane = e_local*4 + h  (16 edges x 4 heads per batch)
// accum phase: lane = hA*16 + d2     (4 heads x 16 channel-pairs)
// mode 0: out[N][128] = relu(concat agg + skip)   (skip incl. bias, from GEMM)
// mode 1: out[N][32]  = mean_h(agg) + skip
__global__ __launch_bounds__(256) void k_attn(
  const float* __restrict__ QKVS, const int* __restrict__ offs,
  const int* __restrict__ srcs, float* __restrict__ out, int mode, int n)
{
  int wv = threadIdx.x>>6, lane = threadIdx.x&63;
  int node = blockIdx.x*4 + wv;
  if(node >= n) return;
  int h = lane & 3;
  int hA = lane >> 4, d2 = lane & 15;
  const float rs = 0.17677669529663687f;  // 1/sqrt(32)
  const float* qp = QKVS + (size_t)node*QKVS_STRIDE + h*32;
  float4 q[8];
  #pragma unroll
  for(int j=0;j<8;j++){
    float4 tq = *(const float4*)(qp + j*4);
    q[j] = make_float4(tq.x*rs, tq.y*rs, tq.z*rs, tq.w*rs);
  }
  int beg = offs[node], end = offs[node+1];
  float m = -__builtin_inff(), s = 0.f;
  float accx = 0.f, accy = 0.f;
  const float* Vbase = QKVS + 256 + hA*32 + d2*2;
  for(int b0 = beg; b0 < end; b0 += 16){
    int nv = end - b0; if(nv > 16) nv = 16;
    int e_l = lane >> 2;
    int idx = b0 + e_l;
    int sj = srcs[(idx < end)? idx : beg];
    const float4* kp = (const float4*)(QKVS + (size_t)sj*QKVS_STRIDE + 128 + h*32);
    float dot = 0.f;
    #pragma unroll
    for(int j=0;j<8;j++){
      float4 kv = kp[j];
      dot += q[j].x*kv.x + q[j].y*kv.y + q[j].z*kv.z + q[j].w*kv.w;
    }
    float logit = (e_l < nv)? dot : -__builtin_inff();
    float bm = logit;
    bm = fmaxf(bm, __shfl_xor(bm,4));
    bm = fmaxf(bm, __shfl_xor(bm,8));
    bm = fmaxf(bm, __shfl_xor(bm,16));
    bm = fmaxf(bm, __shfl_xor(bm,32));
    float mn = fmaxf(m, bm);
    float r = __expf(m - mn);       // m=-inf -> 0
    float p = __expf(logit - mn);   // invalid lanes -> 0
    float ps = p;
    ps += __shfl_xor(ps,4); ps += __shfl_xor(ps,8); ps += __shfl_xor(ps,16); ps += __shfl_xor(ps,32);
    s = r*s + ps; m = mn;
    float racc = __shfl(r, hA);     // r is uniform per h-group; lane hA holds head hA
    accx *= racc; accy *= racc;
    for(int e=0;e<nv;e++){
      float pe = __shfl(p, (e<<2)|hA);
      int se = __shfl(sj, e<<2);
      float2 v2 = *(const float2*)(Vbase + (size_t)se*QKVS_STRIDE);
      accx += pe*v2.x; accy += pe*v2.y;
    }
  }
  float sA = __shfl(s, hA);
  float inv = (sA > 0.f)? (1.f/sA) : 0.f;
  if(mode == 0){
    float ox = accx*inv, oy = accy*inv;
    float2 sk = *(const float2*)(QKVS + (size_t)node*QKVS_STRIDE + 384 + lane*2);
    ox += sk.x; oy += sk.y;
    ox = fmaxf(ox, 0.f); oy = fmaxf(oy, 0.f);
    *(float2*)(out + (size_t)node*128 + lane*2) = make_float2(ox, oy);
  } else {
    float ox = accx*inv*0.25f, oy = accy*inv*0.25f;
    ox += __shfl_xor(ox,16); oy += __shfl_xor(oy,16);
    ox += __shfl_xor(ox,32); oy += __shfl_xor(oy,32);
    if(hA == 0){
      float2 sk = *(const float2*)(QKVS + (size_t)node*QKVS_STRIDE + 384 + d2*2);
      ox += sk.x; oy += sk.y;
      *(float2*)(out + (size_t)node*32 + d2*2) = make_float2(ox, oy);
    }
  }
}

extern "C" void kernel_launch(void* const* d_in, const int* in_sizes, int n_in,
                              void* d_out, int out_size, void* d_ws, size_t ws_size,
                              hipStream_t stream) {
  const float* x = (const float*)d_in[0];
  const int* ei = (const int*)d_in[1];
  int n = in_sizes[0]/DIN;
  int E = in_sizes[1]/2;
  const int* esrc = ei;
  const int* edst = ei + E;

  char* w = (char*)d_ws;
  auto alloc = [&](size_t bytes)->char*{
    char* p = w; w += (bytes + 255) & ~(size_t)255; return p;
  };
  int* offs = (int*)alloc((size_t)(n+1)*4);
  int* deg  = (int*)alloc((size_t)n*4);
  int* cur  = (int*)alloc((size_t)n*4);
  int* part = (int*)alloc(256*4);
  int* srcs = (int*)alloc((size_t)E*4);
  float* qkvs = (float*)alloc((size_t)n*QKVS_STRIDE*4);
  float* h1 = (float*)alloc((size_t)n*128*4);
  float* h2 = (float*)alloc((size_t)n*128*4);

  int SB = (n+255)/256;  // 196 (<=256 required for 2-level scan)
  hipLaunchKernelGGL(k_zero, dim3((n+255)/256), dim3(256), 0, stream, deg, n);
  hipLaunchKernelGGL(k_zero, dim3((n+255)/256), dim3(256), 0, stream, cur, n);
  hipLaunchKernelGGL(k_count, dim3((E+255)/256), dim3(256), 0, stream, edst, deg, E);
  hipLaunchKernelGGL(k_scan1, dim3(SB), dim3(256), 0, stream, deg, offs, part, n);
  hipLaunchKernelGGL(k_scan2, dim3(1), dim3(256), 0, stream, part, SB);
  hipLaunchKernelGGL(k_scan3, dim3(SB), dim3(256), 0, stream, offs, part, n);
  hipLaunchKernelGGL(k_scatter, dim3((E+255)/256), dim3(256), 0, stream, esrc, edst, offs, cur, srcs, E);

  auto f = [&](int i)->const float*{ return (const float*)d_in[i]; };
  int RT = (n+63)/64;
  int AB = (n+3)/4;

  // layer 0
  hipLaunchKernelGGL(k_gemm, dim3(8, RT), dim3(256), 0, stream,
                     x, n, f(2),f(3),f(4),f(5),f(6),f(7),f(8),f(9), 128, qkvs);
  hipLaunchKernelGGL(k_attn, dim3(AB), dim3(256), 0, stream, qkvs, offs, srcs, h1, 0, n);
  // layer 1
  hipLaunchKernelGGL(k_gemm, dim3(8, RT), dim3(256), 0, stream,
                     h1, n, f(10),f(11),f(12),f(13),f(14),f(15),f(16),f(17), 128, qkvs);
  hipLaunchKernelGGL(k_attn, dim3(AB), dim3(256), 0, stream, qkvs, offs, srcs, h2, 0, n);
  // layer 2 (skip width 32, mean over heads)
  hipLaunchKernelGGL(k_gemm, dim3(8, RT), dim3(256), 0, stream,
                     h2, n, f(18),f(19),f(20),f(21),f(22),f(23),f(24),f(25), 32, qkvs);
  hipLaunchKernelGGL(k_attn, dim3(AB), dim3(256), 0, stream, qkvs, offs, srcs, (float*)d_out, 1, n);
}